// Round 5
// baseline (246.060 us; speedup 1.0000x reference)
//
#include <hip/hip_runtime.h>
#include <math.h>

#define B_ 1024
#define D_ 2048
#define M_ 32
#define H_ 32

#define NW 8                 // waves per block == d-columns per block
#define CB 64                // b-rows per chunk
#define NC 8                 // chunks per block -> btile = 512
#define BT (CB * NC)

// Abramowitz & Stegun 7.1.26, |err| <= 1.5e-7 absolute. Uses hw rcp + exp.
__device__ __forceinline__ float fast_erff(float x) {
    float ax = fabsf(x);
    float t  = __builtin_amdgcn_rcpf(1.0f + 0.3275911f * ax);
    float p  = 1.061405429f;
    p = p * t - 1.453152027f;
    p = p * t + 1.421413741f;
    p = p * t - 0.284496736f;
    p = p * t + 0.254829592f;
    float e = __expf(-ax * ax);
    float r = 1.0f - p * t * e;
    return copysignf(r, x);
}

__device__ __forceinline__ float gelu_exact(float x) {
    return 0.5f * x * (1.0f + fast_erff(x * 0.70710678118f));
}

// tanh(x) = 1 - 2/(exp(2x)+1); exp(inf)->inf->rcp->0 gives +/-1 at extremes.
__device__ __forceinline__ float fast_tanhf(float x) {
    return 1.0f - 2.0f * __builtin_amdgcn_rcpf(__expf(2.0f * x) + 1.0f);
}

__global__ __launch_bounds__(512)
void nlm_kernel(const float* __restrict__ pre,
                const float* __restrict__ w1,
                const float* __restrict__ b1,
                const float* __restrict__ w_out,
                const float* __restrict__ b_out,
                float* __restrict__ out) {
    // 2 x 64 KB pre double-buffer (quad-rotation swizzled) + 2 x 2.25 KB out gather
    __shared__ float4 pbuf[2][CB * 64];
    __shared__ float  obuf[2][CB * 9];

    const int tid  = threadIdx.x;
    const int lane = tid & 63;
    const int w    = tid >> 6;          // wave id = d_local
    const int bx   = blockIdx.x;
    const int dt   = bx & 255;          // 256 d-tiles; consecutive blocks walk d
    const int bt   = bx >> 8;           // 0..1
    const int d0   = dt * NW;
    const int b0   = bt * BT;

    // Wave-uniform weights -> SGPR s_load path (round-4 scheme).
    const int du = __builtin_amdgcn_readfirstlane(d0 + w);
    const float* __restrict__ wr  = w1    + (size_t)du * (H_ * M_);
    const float* __restrict__ b1r = b1    + (size_t)du * H_;
    const float* __restrict__ wor = w_out + (size_t)du * H_;
    const float  bo = b_out[du];

    const float4* pre4 = reinterpret_cast<const float4*>(pre);
    // This thread stages rows r = i*8 + w, piece p = lane (64 float4 = 1 KB per row,
    // spanning 8 d x 32 m contiguous in global memory). Coalesced: wave covers one row.

    float4 v[8];
    // ---- prologue: load + swizzle-write chunk 0 ----
#pragma unroll
    for (int i = 0; i < 8; ++i) {
        const int r = i * 8 + w;
        v[i] = pre4[(size_t)(b0 + r) * (D_ * 8) + (size_t)d0 * 8 + lane];
    }
#pragma unroll
    for (int i = 0; i < 8; ++i) {
        const int r = i * 8 + w;
        pbuf[0][r * 64 + ((lane + r) & 63)] = v[i];
    }
    __syncthreads();

    for (int c = 0; c < NC; ++c) {
        const int cur = c & 1;

        // ---- issue next-chunk global loads (latency hides under compute) ----
        if (c + 1 < NC) {
            const int bcn = b0 + (c + 1) * CB;
#pragma unroll
            for (int i = 0; i < 8; ++i) {
                const int r = i * 8 + w;
                v[i] = pre4[(size_t)(bcn + r) * (D_ * 8) + (size_t)d0 * 8 + lane];
            }
        }

        // ---- read my row (b = chunk_base + lane, d = du): 8-way-even bank spread ----
        float4 rv[8];
#pragma unroll
        for (int j = 0; j < 8; ++j)
            rv[j] = pbuf[cur][lane * 64 + ((w * 8 + j + lane) & 63)];

        // ---- compute: h-outer, SGPR weights, 2 FMA chains ----
        float s = 0.f;
#pragma unroll 2
        for (int h = 0; h < H_; ++h) {
            float xe = b1r[h], xo = 0.f;
#pragma unroll
            for (int j = 0; j < 8; ++j) {
                xe = fmaf(rv[j].x, wr[h * M_ + j * 4 + 0], xe);
                xo = fmaf(rv[j].y, wr[h * M_ + j * 4 + 1], xo);
                xe = fmaf(rv[j].z, wr[h * M_ + j * 4 + 2], xe);
                xo = fmaf(rv[j].w, wr[h * M_ + j * 4 + 3], xo);
            }
            const float x = xe + xo;
            s = fmaf(gelu_exact(x), wor[h], s);
        }
        obuf[cur][lane * 9 + w] = fast_tanhf(s + bo);   // pad 9: 2-way banks, free

        // ---- swizzle-write next chunk into the other buffer ----
        if (c + 1 < NC) {
            const int nxt = (c + 1) & 1;
#pragma unroll
            for (int i = 0; i < 8; ++i) {
                const int r = i * 8 + w;
                pbuf[nxt][r * 64 + ((lane + r) & 63)] = v[i];
            }
        }
        __syncthreads();

        // ---- flush chunk c outputs: 8 consecutive threads -> 32 B contiguous ----
        {
            const int b = tid >> 3, j = tid & 7;
            out[(size_t)(b0 + c * CB + b) * D_ + d0 + j] = obuf[cur][b * 9 + j];
        }
    }
}

extern "C" void kernel_launch(void* const* d_in, const int* in_sizes, int n_in,
                              void* d_out, int out_size, void* d_ws, size_t ws_size,
                              hipStream_t stream) {
    const float* pre   = (const float*)d_in[0];
    const float* w1    = (const float*)d_in[1];
    const float* b1    = (const float*)d_in[2];
    const float* w_out = (const float*)d_in[3];
    const float* b_out = (const float*)d_in[4];
    float* out = (float*)d_out;

    const int grid = (D_ / NW) * (B_ / BT);   // 256 * 2 = 512 blocks, 2 per CU
    nlm_kernel<<<dim3(grid), dim3(512), 0, stream>>>(pre, w1, b1, w_out, b_out, out);
}

// Round 6
// 133.765 us; speedup vs baseline: 1.8395x; 1.8395x over previous
//
#include <hip/hip_runtime.h>
#include <math.h>

#define B_ 1024
#define D_ 2048
#define M_ 32
#define H_ 32

#define DPB 32        // d per block -> each 128-B out line wholly owned by one block
#define DPW 8         // d per wave, processed sequentially
#define CB  64        // b per block (lane = b)
#define OPAD 33       // out-gather pad: bank = (lane + col) % 32 -> 2-way, free

// Abramowitz & Stegun 7.1.26, |err| <= 1.5e-7 absolute. Uses hw rcp + exp.
__device__ __forceinline__ float fast_erff(float x) {
    float ax = fabsf(x);
    float t  = __builtin_amdgcn_rcpf(1.0f + 0.3275911f * ax);
    float p  = 1.061405429f;
    p = p * t - 1.453152027f;
    p = p * t + 1.421413741f;
    p = p * t - 0.284496736f;
    p = p * t + 0.254829592f;
    float e = __expf(-ax * ax);
    float r = 1.0f - p * t * e;
    return copysignf(r, x);
}

__device__ __forceinline__ float gelu_exact(float x) {
    return 0.5f * x * (1.0f + fast_erff(x * 0.70710678118f));
}

// tanh(x) = 1 - 2/(exp(2x)+1); exp(inf)->inf->rcp->0 gives +/-1 at extremes.
__device__ __forceinline__ float fast_tanhf(float x) {
    return 1.0f - 2.0f * __builtin_amdgcn_rcpf(__expf(2.0f * x) + 1.0f);
}

// Compute one (b, d) output from a register-held pre row V[8] (float4) and
// wave-uniform (SGPR) weight pointers. Macro keeps V statically indexed.
#define COMPUTE_COL(V, DD)                                                     \
    {                                                                          \
        const float* __restrict__ wr  = w1    + (size_t)(DD) * (H_ * M_);      \
        const float* __restrict__ b1r = b1    + (size_t)(DD) * H_;             \
        const float* __restrict__ wor = w_out + (size_t)(DD) * H_;             \
        const float  bo = b_out[(DD)];                                         \
        float s = 0.f;                                                         \
        _Pragma("unroll 2")                                                    \
        for (int h = 0; h < H_; ++h) {                                         \
            float xe = b1r[h], xo = 0.f;                                       \
            _Pragma("unroll")                                                  \
            for (int mg = 0; mg < 8; ++mg) {                                   \
                xe = fmaf(V[mg].x, wr[h * M_ + mg * 4 + 0], xe);               \
                xo = fmaf(V[mg].y, wr[h * M_ + mg * 4 + 1], xo);               \
                xe = fmaf(V[mg].z, wr[h * M_ + mg * 4 + 2], xe);               \
                xo = fmaf(V[mg].w, wr[h * M_ + mg * 4 + 3], xo);               \
            }                                                                  \
            s = fmaf(gelu_exact(xe + xo), wor[h], s);                          \
        }                                                                      \
        obuf[lane * OPAD + ((DD) - d0)] = fast_tanhf(s + bo);                  \
    }

__global__ __launch_bounds__(256)
void nlm_kernel(const float* __restrict__ pre,
                const float* __restrict__ w1,
                const float* __restrict__ b1,
                const float* __restrict__ w_out,
                const float* __restrict__ b_out,
                float* __restrict__ out) {
    __shared__ float obuf[CB * OPAD];   // 8.45 KB

    const int tid  = threadIdx.x;
    const int lane = tid & 63;
    const int w    = tid >> 6;                 // 0..3
    const int bx   = blockIdx.x;
    const int dt   = bx >> 4;                  // 0..63
    const int bt   = bx & 15;                  // 0..15: consecutive blocks share w1 slice
    const int d0   = dt * DPB;
    const int b0   = bt * CB;
    const int b    = b0 + lane;

    // Wave-uniform d base -> SGPR weight addressing (s_load path).
    const int du = __builtin_amdgcn_readfirstlane(d0 + w * DPW);

    // Lane's pre base: all 64 row-loads are this base + immediate offsets
    // (d-walk is +128 B, mg-walk is +16 B; max imm 1008 < 4096).
    const float* __restrict__ prow = pre + ((size_t)b * D_ + du) * M_;

    // ---- software-pipelined d-loop: ping-pong vA/vB, statically indexed ----
    float4 vA[8], vB[8];
#pragma unroll
    for (int mg = 0; mg < 8; ++mg)
        vA[mg] = *reinterpret_cast<const float4*>(prow + mg * 4);

#pragma unroll
    for (int i = 0; i < DPW; i += 2) {
        // issue loads for d = du+i+1 before computing d = du+i
#pragma unroll
        for (int mg = 0; mg < 8; ++mg)
            vB[mg] = *reinterpret_cast<const float4*>(prow + (i + 1) * M_ + mg * 4);

        COMPUTE_COL(vA, du + i)

        if (i + 2 < DPW) {
#pragma unroll
            for (int mg = 0; mg < 8; ++mg)
                vA[mg] = *reinterpret_cast<const float4*>(prow + (i + 2) * M_ + mg * 4);
        }

        COMPUTE_COL(vB, du + i + 1)
    }

    __syncthreads();

    // ---- flush: every wave-store = 2 rows x 128 B = 2 full lines, fully dirty ----
    {
        const int j  = tid & 31;       // col within d-tile
        const int r0 = tid >> 5;       // 0..7
#pragma unroll
        for (int k = 0; k < 8; ++k) {
            const int r = r0 + k * 8;  // 0..63
            out[(size_t)(b0 + r) * D_ + d0 + j] = obuf[r * OPAD + j];
        }
    }
}

extern "C" void kernel_launch(void* const* d_in, const int* in_sizes, int n_in,
                              void* d_out, int out_size, void* d_ws, size_t ws_size,
                              hipStream_t stream) {
    const float* pre   = (const float*)d_in[0];
    const float* w1    = (const float*)d_in[1];
    const float* b1    = (const float*)d_in[2];
    const float* w_out = (const float*)d_in[3];
    const float* b_out = (const float*)d_in[4];
    float* out = (float*)d_out;

    const int grid = (D_ / DPB) * (B_ / CB);   // 64 * 16 = 1024
    nlm_kernel<<<dim3(grid), dim3(256), 0, stream>>>(pre, w1, b1, w_out, b_out, out);
}

// Round 7
// 113.224 us; speedup vs baseline: 2.1732x; 1.1814x over previous
//
#include <hip/hip_runtime.h>
#include <math.h>

#define B_ 1024
#define D_ 2048
#define M_ 32
#define H_ 32

#define DPB 16        // d per block
#define DPW 4         // d per wave, sequential (wave-uniform d -> SGPR weights)
#define CB  64        // b per block = lanes per wave
#define OPAD 17       // out-gather pad

// Abramowitz & Stegun 7.1.26, |err| <= 1.5e-7 absolute. Uses hw rcp + exp.
__device__ __forceinline__ float fast_erff(float x) {
    float ax = fabsf(x);
    float t  = __builtin_amdgcn_rcpf(1.0f + 0.3275911f * ax);
    float p  = 1.061405429f;
    p = p * t - 1.453152027f;
    p = p * t + 1.421413741f;
    p = p * t - 0.284496736f;
    p = p * t + 0.254829592f;
    float e = __expf(-ax * ax);
    float r = 1.0f - p * t * e;
    return copysignf(r, x);
}

__device__ __forceinline__ float gelu_exact(float x) {
    return 0.5f * x * (1.0f + fast_erff(x * 0.70710678118f));
}

// tanh(x) = 1 - 2/(exp(2x)+1); exp(inf)->inf->rcp->0 gives +/-1 at extremes.
__device__ __forceinline__ float fast_tanhf(float x) {
    return 1.0f - 2.0f * __builtin_amdgcn_rcpf(__expf(2.0f * x) + 1.0f);
}

__global__ __launch_bounds__(256, 8)   // force VGPR<=64 -> 8 waves/SIMD
void nlm_kernel(const float* __restrict__ pre,
                const float* __restrict__ w1,
                const float* __restrict__ b1,
                const float* __restrict__ w_out,
                const float* __restrict__ b_out,
                float* __restrict__ out) {
    __shared__ float obuf[CB * OPAD];   // 4.35 KB

    const int tid  = threadIdx.x;
    const int lane = tid & 63;
    const int w    = tid >> 6;                  // 0..3
    const int bx   = blockIdx.x;
    const int dt   = bx & (D_ / DPB - 1);       // 0..127: consecutive blocks walk d
    const int bt   = bx >> 7;                   // 0..15
    const int d0   = dt * DPB;
    const int b0   = bt * CB;
    const int b    = b0 + lane;

    // Wave-uniform d base -> SGPR weight addressing (s_load path).
    const int du = __builtin_amdgcn_readfirstlane(d0 + w * DPW);

    // All 32 row-loads (4 d x 8 float4) = one base + immediate offsets.
    const float* __restrict__ prow = pre + ((size_t)b * D_ + du) * M_;

#pragma unroll
    for (int i = 0; i < DPW; ++i) {
        // ---- load this d's pre row into registers (single buffer; TLP hides) ----
        float4 rv[8];
#pragma unroll
        for (int mg = 0; mg < 8; ++mg)
            rv[mg] = *reinterpret_cast<const float4*>(prow + i * M_ + mg * 4);

        const int dd = du + i;
        const float* __restrict__ wr  = w1    + (size_t)dd * (H_ * M_);
        const float* __restrict__ b1r = b1    + (size_t)dd * H_;
        const float* __restrict__ wor = w_out + (size_t)dd * H_;
        const float  bo = b_out[dd];

        float s = 0.f;
#pragma unroll 2
        for (int h = 0; h < H_; ++h) {
            float xe = b1r[h], xo = 0.f;
#pragma unroll
            for (int mg = 0; mg < 8; ++mg) {
                xe = fmaf(rv[mg].x, wr[h * M_ + mg * 4 + 0], xe);
                xo = fmaf(rv[mg].y, wr[h * M_ + mg * 4 + 1], xo);
                xe = fmaf(rv[mg].z, wr[h * M_ + mg * 4 + 2], xe);
                xo = fmaf(rv[mg].w, wr[h * M_ + mg * 4 + 3], xo);
            }
            s = fmaf(gelu_exact(xe + xo), wor[h], s);
        }
        obuf[lane * OPAD + (w * DPW + i)] = fast_tanhf(s + bo);
    }

    __syncthreads();

    // ---- flush: thread t -> row r=t>>2, 16-B chunk c=(t&3)*4; dwordx4 stores ----
    {
        const int r = tid >> 2;
        const int c = (tid & 3) * 4;
        float4 o;
        o.x = obuf[r * OPAD + c + 0];
        o.y = obuf[r * OPAD + c + 1];
        o.z = obuf[r * OPAD + c + 2];
        o.w = obuf[r * OPAD + c + 3];
        *reinterpret_cast<float4*>(out + (size_t)(b0 + r) * D_ + d0 + c) = o;
    }
}

extern "C" void kernel_launch(void* const* d_in, const int* in_sizes, int n_in,
                              void* d_out, int out_size, void* d_ws, size_t ws_size,
                              hipStream_t stream) {
    const float* pre   = (const float*)d_in[0];
    const float* w1    = (const float*)d_in[1];
    const float* b1    = (const float*)d_in[2];
    const float* w_out = (const float*)d_in[3];
    const float* b_out = (const float*)d_in[4];
    float* out = (float*)d_out;

    const int grid = (D_ / DPB) * (B_ / CB);   // 128 * 16 = 2048 = 8 blocks/CU
    nlm_kernel<<<dim3(grid), dim3(256), 0, stream>>>(pre, w1, b1, w_out, b_out, out);
}